// Round 1
// baseline (249.621 us; speedup 1.0000x reference)
//
#include <hip/hip_runtime.h>
#include <hip/hip_bf16.h>

#define IN_F   1024
#define OUT_F  1024
#define GRID_N 8
#define TOKENS 8192
#define KTOT   (IN_F + IN_F * GRID_N)   // 9216

#define BM 128
#define BN 128
#define BK 32

typedef __attribute__((ext_vector_type(8))) short  bf16x8;
typedef __attribute__((ext_vector_type(4))) float  f32x4;

// f32 -> bf16 bits, round-to-nearest-even
__device__ __forceinline__ unsigned int f2bf(float f) {
    union { float f; unsigned int u; } v; v.f = f;
    unsigned int r = v.u + 0x7fffu + ((v.u >> 16) & 1u);
    return r >> 16;
}

// One thread per (t, i): writes silu(x) into A[t][i] and the 8 RBF basis
// values into A[t][1024 + i*8 .. +8) as one 16B store.
__global__ __launch_bounds__(256)
void prep_a_kernel(const float* __restrict__ x, const float* __restrict__ grid,
                   unsigned short* __restrict__ A)
{
    int idx = blockIdx.x * blockDim.x + threadIdx.x;
    int t = idx >> 10;          // / IN_F
    int i = idx & 1023;
    float xv = x[idx];
    float sil = xv / (1.0f + __expf(-xv));
    A[(size_t)t * KTOT + i] = (unsigned short)f2bf(sil);

    const float invd = 1.0f / (2.0f / 7.0f + 1e-5f);
    float gv[8];
    #pragma unroll
    for (int g = 0; g < 8; ++g) gv[g] = grid[g];
    unsigned int h[8];
    #pragma unroll
    for (int g = 0; g < 8; ++g) {
        float d = (xv - gv[g]) * invd;
        h[g] = f2bf(__expf(-d * d));
    }
    uint4 pk;
    pk.x = h[0] | (h[1] << 16);
    pk.y = h[2] | (h[3] << 16);
    pk.z = h[4] | (h[5] << 16);
    pk.w = h[6] | (h[7] << 16);
    *reinterpret_cast<uint4*>(&A[(size_t)t * KTOT + IN_F + (size_t)i * 8]) = pk;
}

// Repack W [O,1024] and spline [O,1024,8] into bf16 B [O, 9216].
// One thread per 8 output elements.
__global__ __launch_bounds__(256)
void prep_b_kernel(const float* __restrict__ W, const float* __restrict__ spl,
                   unsigned short* __restrict__ B)
{
    int idx = blockIdx.x * blockDim.x + threadIdx.x;
    int o  = idx / (KTOT / 8);            // KTOT/8 = 1152
    int c8 = idx - o * (KTOT / 8);
    const float* src = (c8 < IN_F / 8)
        ? (W   + (size_t)o * IN_F            + (size_t)c8 * 8)
        : (spl + (size_t)o * (IN_F * GRID_N) + (size_t)(c8 - IN_F / 8) * 8);
    const float4* s4 = reinterpret_cast<const float4*>(src);
    float4 lo = s4[0], hi = s4[1];
    uint4 pk;
    pk.x = f2bf(lo.x) | (f2bf(lo.y) << 16);
    pk.y = f2bf(lo.z) | (f2bf(lo.w) << 16);
    pk.z = f2bf(hi.x) | (f2bf(hi.y) << 16);
    pk.w = f2bf(hi.z) | (f2bf(hi.w) << 16);
    *reinterpret_cast<uint4*>(&B[(size_t)o * KTOT + (size_t)c8 * 8]) = pk;
}

// C[rows, OUT_F] = A[rows, KTOT] @ B[OUT_F, KTOT]^T + bias
// m97 structure: 128x128 tile, BK=32, 4 waves (2x2 of 64x64 subtiles),
// mfma_f32_16x16x32_bf16, global_load_lds width=16 staging.
__global__ __launch_bounds__(256)
void gemm_kan(const unsigned short* __restrict__ A,
              const unsigned short* __restrict__ B,
              const float* __restrict__ bias,
              float* __restrict__ C)
{
    __shared__ unsigned short sA[BM * BK];   // [row][k], 8 KB
    __shared__ unsigned short sB[BN * BK];   // [col][k], 8 KB

    const int bid  = blockIdx.x;
    const int bn   = bid & 7;     // % (OUT_F/BN): round-robin XCD keeps B-panel in its L2
    const int bm   = bid >> 3;
    const int tid  = threadIdx.x;
    const int wave = tid >> 6;
    const int lane = tid & 63;
    const int wr   = wave >> 1;
    const int wc   = wave & 1;

    const f32x4 zero = {0.f, 0.f, 0.f, 0.f};
    f32x4 acc[4][4];
    #pragma unroll
    for (int m = 0; m < 4; ++m)
        #pragma unroll
        for (int n = 0; n < 4; ++n) acc[m][n] = zero;

    const int row = lane & 15;    // fragment row/col within 16
    const int kg  = lane >> 4;    // k-group 0..3 (8 k each)

    const size_t aBase = (size_t)bm * BM * KTOT;
    const size_t bBase = (size_t)bn * BN * KTOT;

    for (int kt = 0; kt < KTOT; kt += BK) {
        __syncthreads();   // previous iter's LDS reads done before overwrite
        #pragma unroll
        for (int r = 0; r < 2; ++r) {
            const int chunk = r * 256 + wave * 64 + lane;      // 512 x 16B per tile
            const int trow  = chunk >> 2;                      // 4 chunks per row (64B)
            const int tcol  = (chunk & 3) * 8;
            const unsigned short* gA = A + aBase + (size_t)trow * KTOT + kt + tcol;
            const unsigned short* gB = B + bBase + (size_t)trow * KTOT + kt + tcol;
            const unsigned int ldsOff = (unsigned)(r * 256 + wave * 64) * 16; // wave-uniform base
            __builtin_amdgcn_global_load_lds(
                (const __attribute__((address_space(1))) void*)gA,
                (__attribute__((address_space(3))) void*)((char*)sA + ldsOff),
                16, 0, 0);
            __builtin_amdgcn_global_load_lds(
                (const __attribute__((address_space(1))) void*)gB,
                (__attribute__((address_space(3))) void*)((char*)sB + ldsOff),
                16, 0, 0);
        }
        __syncthreads();   // vmcnt(0) drain before barrier covers global_load_lds

        bf16x8 af[4], bfr[4];
        #pragma unroll
        for (int m = 0; m < 4; ++m)
            af[m] = *reinterpret_cast<const bf16x8*>(
                &sA[(wr * 64 + m * 16 + row) * BK + kg * 8]);
        #pragma unroll
        for (int n = 0; n < 4; ++n)
            bfr[n] = *reinterpret_cast<const bf16x8*>(
                &sB[(wc * 64 + n * 16 + row) * BK + kg * 8]);
        #pragma unroll
        for (int m = 0; m < 4; ++m)
            #pragma unroll
            for (int n = 0; n < 4; ++n)
                acc[m][n] = __builtin_amdgcn_mfma_f32_16x16x32_bf16(
                    af[m], bfr[n], acc[m][n], 0, 0, 0);
    }

    // Epilogue: C/D layout col = lane&15, row = (lane>>4)*4 + j  (m89/m91 verified)
    const size_t orow0 = (size_t)bm * BM + (size_t)wr * 64;
    const int    ocol0 = bn * BN + wc * 64;
    #pragma unroll
    for (int n = 0; n < 4; ++n) {
        const int col = ocol0 + n * 16 + row;
        const float bv = bias[col];
        #pragma unroll
        for (int m = 0; m < 4; ++m) {
            #pragma unroll
            for (int j = 0; j < 4; ++j) {
                const size_t orow = orow0 + m * 16 + kg * 4 + j;
                C[orow * OUT_F + col] = acc[m][n][j] + bv;
            }
        }
    }
}

extern "C" void kernel_launch(void* const* d_in, const int* in_sizes, int n_in,
                              void* d_out, int out_size, void* d_ws, size_t ws_size,
                              hipStream_t stream)
{
    const float* x    = (const float*)d_in[0];
    const float* W    = (const float*)d_in[1];
    const float* bias = (const float*)d_in[2];
    const float* spl  = (const float*)d_in[3];
    const float* grid = (const float*)d_in[4];
    float* out = (float*)d_out;

    unsigned short* Bw = (unsigned short*)d_ws;                  // [OUT_F][KTOT] bf16
    unsigned short* Aw = Bw + (size_t)OUT_F * KTOT;              // [chunk][KTOT] bf16

    // Workspace-aware M-chunking (needs 19 MB for B + 151 MB for full A).
    const size_t bBytes = (size_t)OUT_F * KTOT * 2;
    size_t avail = ws_size > bBytes ? ws_size - bBytes : 0;
    long maxRows = (long)(avail / ((size_t)KTOT * 2));
    int chunk = (maxRows >= TOKENS) ? TOKENS : (int)((maxRows / BM) * BM);
    if (chunk < BM) chunk = BM;   // last resort

    prep_b_kernel<<<(OUT_F * (KTOT / 8)) / 256, 256, 0, stream>>>(W, spl, Bw);

    for (int t0 = 0; t0 < TOKENS; t0 += chunk) {
        int rows = (TOKENS - t0 < chunk) ? (TOKENS - t0) : chunk;
        prep_a_kernel<<<(rows * IN_F) / 256, 256, 0, stream>>>(
            x + (size_t)t0 * IN_F, grid, Aw);
        gemm_kan<<<(rows / BM) * (OUT_F / BN), 256, 0, stream>>>(
            Aw, Bw, bias, out + (size_t)t0 * OUT_F);
    }
}

// Round 2
// 203.615 us; speedup vs baseline: 1.2259x; 1.2259x over previous
//
#include <hip/hip_runtime.h>
#include <hip/hip_bf16.h>

#define IN_F   1024
#define OUT_F  1024
#define GRID_N 8
#define TOKENS 8192
#define KTOT   9216
#define KHALF  4608
#define NTILE  72          // KHALF / 64

typedef __attribute__((ext_vector_type(8))) short  bf16x8;
typedef __attribute__((ext_vector_type(4))) float  f32x4;

struct TrueT  { static constexpr bool value = true;  };
struct FalseT { static constexpr bool value = false; };

__device__ __forceinline__ unsigned int f2bf(float f) {
    union { float f; unsigned int u; } v; v.f = f;
    unsigned int r = v.u + 0x7fffu + ((v.u >> 16) & 1u);
    return r >> 16;
}

// One thread per (t, i): silu(x) -> A[t][i]; 8 RBF basis -> A[t][1024+i*8..] (16B store)
__global__ __launch_bounds__(256)
void prep_a_kernel(const float* __restrict__ x, const float* __restrict__ grid,
                   unsigned short* __restrict__ A)
{
    int idx = blockIdx.x * blockDim.x + threadIdx.x;
    int t = idx >> 10;
    int i = idx & 1023;
    float xv = x[idx];
    float sil = xv / (1.0f + __expf(-xv));
    A[(size_t)t * KTOT + i] = (unsigned short)f2bf(sil);

    const float invd = 1.0f / (2.0f / 7.0f + 1e-5f);
    unsigned int h[8];
    #pragma unroll
    for (int g = 0; g < 8; ++g) {
        float d = (xv - grid[g]) * invd;
        h[g] = f2bf(__expf(-d * d));
    }
    uint4 pk;
    pk.x = h[0] | (h[1] << 16);
    pk.y = h[2] | (h[3] << 16);
    pk.z = h[4] | (h[5] << 16);
    pk.w = h[6] | (h[7] << 16);
    *reinterpret_cast<uint4*>(&A[(size_t)t * KTOT + IN_F + (size_t)i * 8]) = pk;
}

// Repack W [O,1024] and spline [O,1024,8] into bf16 B [O, 9216].
__global__ __launch_bounds__(256)
void prep_b_kernel(const float* __restrict__ W, const float* __restrict__ spl,
                   unsigned short* __restrict__ B)
{
    int idx = blockIdx.x * blockDim.x + threadIdx.x;
    int o  = idx / (KTOT / 8);
    int c8 = idx - o * (KTOT / 8);
    const float* src = (c8 < IN_F / 8)
        ? (W   + (size_t)o * IN_F            + (size_t)c8 * 8)
        : (spl + (size_t)o * (IN_F * GRID_N) + (size_t)(c8 - IN_F / 8) * 8);
    const float4* s4 = reinterpret_cast<const float4*>(src);
    float4 lo = s4[0], hi = s4[1];
    uint4 pk;
    pk.x = f2bf(lo.x) | (f2bf(lo.y) << 16);
    pk.y = f2bf(lo.z) | (f2bf(lo.w) << 16);
    pk.z = f2bf(hi.x) | (f2bf(hi.y) << 16);
    pk.w = f2bf(hi.z) | (f2bf(hi.w) << 16);
    *reinterpret_cast<uint4*>(&B[(size_t)o * KTOT + (size_t)c8 * 8]) = pk;
}

// ---------------------------------------------------------------------------
// 256x256 tile, BK=64, 8 waves (2M x 4N, per-wave 128x64), split-K=2.
// 4 phases per K-tile, 16 MFMA/phase, raw s_barrier + counted staging,
// XOR-swizzled LDS (linear gload_lds dest + inverse-swizzled global source).
// Writes f32 partials P[sk][row][col] (no bias).
// ---------------------------------------------------------------------------
#define GLOAD(src, dst) __builtin_amdgcn_global_load_lds( \
    (const __attribute__((address_space(1))) void*)(src),  \
    (__attribute__((address_space(3))) void*)(dst), 16, 0, 0)
#define SBAR()  __builtin_amdgcn_s_barrier()
#define SCH0()  __builtin_amdgcn_sched_barrier(0)
#define LGKM0() asm volatile("s_waitcnt lgkmcnt(0)" ::: "memory")
#define VMC0()  asm volatile("s_waitcnt vmcnt(0)" ::: "memory")

__global__ __launch_bounds__(512, 2)
void gemm_kan2(const unsigned short* __restrict__ A,
               const unsigned short* __restrict__ B,
               float* __restrict__ P, int rows)
{
    __shared__ char lds[131072];   // 2 bufs x (A 32KB + B 32KB)

    const int bid  = blockIdx.x;
    const int sk   = bid & 1;            // XCD = bid&7 owns one (bn,sk) pair:
    const int bn   = (bid >> 1) & 3;     // B-panel slice 2.36 MB stays in its L2
    const int bm   = bid >> 3;
    const int tid  = threadIdx.x;
    const int wave = tid >> 6, lane = tid & 63;
    const int wr   = wave >> 2, wc = wave & 3;
    const int row  = lane & 15, kg = lane >> 4;
    const int sw   = row & 7;
    const int koff[2] = { (kg ^ sw) * 16, ((4 | kg) ^ sw) * 16 };
    const int l3 = lane >> 3, l7 = lane & 7;
    const int ksrc = (l7 ^ l3) * 8;      // inverse-swizzled source k offset
    const int k0 = sk * KHALF;

    // staging pointers (advance by 64 elems per staged K-tile)
    const unsigned short* gA[4];
    const unsigned short* gB[4];
    #pragma unroll
    for (int r = 0; r < 4; ++r) {
        gA[r] = A + (size_t)(bm * 256 + wave * 32 + r * 8 + l3) * KTOT + k0 + ksrc;
        gB[r] = B + (size_t)(bn * 256 + wave * 32 + r * 8 + l3) * KTOT + k0 + ksrc;
    }

    f32x4 acc[8][4];
    const f32x4 zero = {0.f, 0.f, 0.f, 0.f};
    #pragma unroll
    for (int m = 0; m < 8; ++m)
        #pragma unroll
        for (int n = 0; n < 4; ++n) acc[m][n] = zero;

    // prologue: stage T0 -> buf0
    {
        char* dA = lds + wave * 4096;
        char* dB = lds + 32768 + wave * 4096;
        #pragma unroll
        for (int r = 0; r < 4; ++r) GLOAD(gA[r], dA + r * 1024);
        #pragma unroll
        for (int r = 0; r < 4; ++r) GLOAD(gB[r], dB + r * 1024);
        #pragma unroll
        for (int r = 0; r < 4; ++r) { gA[r] += 64; gB[r] += 64; }
    }
    VMC0(); SBAR(); SCH0();

    const int aB = (wr * 128 + row) * 128;           // + m*2048
    const int bB = 32768 + (wc * 64 + row) * 128;    // + n*2048

    bf16x8 af[4][2], bf[2][2];
    int u = 0;

    auto tile = [&](auto stC) {
        constexpr bool ST = decltype(stC)::value;
        char* bufc = lds + (u & 1) * 65536;
        char* bufn = lds + ((u & 1) ^ 1) * 65536;

        // ---- phase 1: mh=0, nh=0 (A-half0 + B n0-1; stage next A) ----
        #pragma unroll
        for (int mi = 0; mi < 4; ++mi)
            #pragma unroll
            for (int ks = 0; ks < 2; ++ks)
                af[mi][ks] = *(const bf16x8*)(bufc + aB + mi * 2048 + koff[ks]);
        #pragma unroll
        for (int ni = 0; ni < 2; ++ni)
            #pragma unroll
            for (int ks = 0; ks < 2; ++ks)
                bf[ni][ks] = *(const bf16x8*)(bufc + bB + ni * 2048 + koff[ks]);
        if constexpr (ST) {
            #pragma unroll
            for (int r = 0; r < 4; ++r)
                GLOAD(gA[r], bufn + wave * 4096 + r * 1024);
        }
        SBAR(); SCH0(); LGKM0(); SCH0();
        __builtin_amdgcn_s_setprio(1);
        #pragma unroll
        for (int mi = 0; mi < 4; ++mi)
            #pragma unroll
            for (int ni = 0; ni < 2; ++ni)
                #pragma unroll
                for (int ks = 0; ks < 2; ++ks)
                    acc[mi][ni] = __builtin_amdgcn_mfma_f32_16x16x32_bf16(
                        af[mi][ks], bf[ni][ks], acc[mi][ni], 0, 0, 0);
        __builtin_amdgcn_s_setprio(0);
        SBAR(); SCH0();

        // ---- phase 2: mh=0, nh=1 (B n2-3; stage next B half) ----
        #pragma unroll
        for (int ni = 0; ni < 2; ++ni)
            #pragma unroll
            for (int ks = 0; ks < 2; ++ks)
                bf[ni][ks] = *(const bf16x8*)(bufc + bB + (2 + ni) * 2048 + koff[ks]);
        if constexpr (ST) {
            #pragma unroll
            for (int r = 0; r < 2; ++r)
                GLOAD(gB[r], bufn + 32768 + wave * 4096 + r * 1024);
        }
        SBAR(); SCH0(); LGKM0(); SCH0();
        __builtin_amdgcn_s_setprio(1);
        #pragma unroll
        for (int mi = 0; mi < 4; ++mi)
            #pragma unroll
            for (int ni = 0; ni < 2; ++ni)
                #pragma unroll
                for (int ks = 0; ks < 2; ++ks)
                    acc[mi][2 + ni] = __builtin_amdgcn_mfma_f32_16x16x32_bf16(
                        af[mi][ks], bf[ni][ks], acc[mi][2 + ni], 0, 0, 0);
        __builtin_amdgcn_s_setprio(0);
        SBAR(); SCH0();

        // ---- phase 3: mh=1, nh=0 (A-half1 + B n0-1; stage next B half) ----
        #pragma unroll
        for (int mi = 0; mi < 4; ++mi)
            #pragma unroll
            for (int ks = 0; ks < 2; ++ks)
                af[mi][ks] = *(const bf16x8*)(bufc + aB + (4 + mi) * 2048 + koff[ks]);
        #pragma unroll
        for (int ni = 0; ni < 2; ++ni)
            #pragma unroll
            for (int ks = 0; ks < 2; ++ks)
                bf[ni][ks] = *(const bf16x8*)(bufc + bB + ni * 2048 + koff[ks]);
        if constexpr (ST) {
            #pragma unroll
            for (int r = 2; r < 4; ++r)
                GLOAD(gB[r], bufn + 32768 + wave * 4096 + r * 1024);
        }
        SBAR(); SCH0(); LGKM0(); SCH0();
        __builtin_amdgcn_s_setprio(1);
        #pragma unroll
        for (int mi = 0; mi < 4; ++mi)
            #pragma unroll
            for (int ni = 0; ni < 2; ++ni)
                #pragma unroll
                for (int ks = 0; ks < 2; ++ks)
                    acc[4 + mi][ni] = __builtin_amdgcn_mfma_f32_16x16x32_bf16(
                        af[mi][ks], bf[ni][ks], acc[4 + mi][ni], 0, 0, 0);
        __builtin_amdgcn_s_setprio(0);
        SBAR(); SCH0();

        // ---- phase 4: mh=1, nh=1 (B n2-3; end-of-tile drain) ----
        #pragma unroll
        for (int ni = 0; ni < 2; ++ni)
            #pragma unroll
            for (int ks = 0; ks < 2; ++ks)
                bf[ni][ks] = *(const bf16x8*)(bufc + bB + (2 + ni) * 2048 + koff[ks]);
        SBAR(); SCH0(); LGKM0(); SCH0();
        __builtin_amdgcn_s_setprio(1);
        #pragma unroll
        for (int mi = 0; mi < 4; ++mi)
            #pragma unroll
            for (int ni = 0; ni < 2; ++ni)
                #pragma unroll
                for (int ks = 0; ks < 2; ++ks)
                    acc[4 + mi][2 + ni] = __builtin_amdgcn_mfma_f32_16x16x32_bf16(
                        af[mi][ks], bf[ni][ks], acc[4 + mi][2 + ni], 0, 0, 0);
        __builtin_amdgcn_s_setprio(0);
        VMC0();            // next tile resident after the barrier
        SBAR(); SCH0();

        if constexpr (ST) {
            #pragma unroll
            for (int r = 0; r < 4; ++r) { gA[r] += 64; gB[r] += 64; }
        }
    };

    for (u = 0; u < NTILE - 1; ++u) tile(TrueT{});
    tile(FalseT{});

    // epilogue: write f32 partials
    float* Pp = P + (size_t)sk * rows * OUT_F;
    const size_t orow0 = (size_t)bm * 256 + (size_t)wr * 128;
    const int    ocol0 = bn * 256 + wc * 64;
    #pragma unroll
    for (int n = 0; n < 4; ++n) {
        const int col = ocol0 + n * 16 + row;
        #pragma unroll
        for (int m = 0; m < 8; ++m) {
            #pragma unroll
            for (int j = 0; j < 4; ++j)
                Pp[(orow0 + m * 16 + kg * 4 + j) * OUT_F + col] = acc[m][n][j];
        }
    }
}

// out = P0 + P1 + bias
__global__ __launch_bounds__(256)
void reduce_kan(const float* __restrict__ P, const float* __restrict__ bias,
                float* __restrict__ out, int n4, int skStride4)
{
    const float4* p0 = (const float4*)P;
    const float4* p1 = p0 + skStride4;
    const float4* bv = (const float4*)bias;
    float4* o = (float4*)out;
    for (int i = blockIdx.x * blockDim.x + threadIdx.x; i < n4;
         i += gridDim.x * blockDim.x) {
        float4 a = p0[i], b = p1[i], c = bv[i & 255];
        float4 r;
        r.x = a.x + b.x + c.x;  r.y = a.y + b.y + c.y;
        r.z = a.z + b.z + c.z;  r.w = a.w + b.w + c.w;
        o[i] = r;
    }
}

extern "C" void kernel_launch(void* const* d_in, const int* in_sizes, int n_in,
                              void* d_out, int out_size, void* d_ws, size_t ws_size,
                              hipStream_t stream)
{
    const float* x    = (const float*)d_in[0];
    const float* W    = (const float*)d_in[1];
    const float* bias = (const float*)d_in[2];
    const float* spl  = (const float*)d_in[3];
    const float* grid = (const float*)d_in[4];
    float* out = (float*)d_out;

    unsigned short* Bw = (unsigned short*)d_ws;               // 18.9 MB
    unsigned short* Aw = Bw + (size_t)OUT_F * KTOT;

    // per-row ws: A bf16 (18432 B) + 2x f32 partial (8192 B)
    const size_t bBytes = (size_t)OUT_F * KTOT * 2;
    size_t avail = ws_size > bBytes ? ws_size - bBytes : 0;
    long maxRows = (long)(avail / 26624);
    int chunk = (maxRows >= TOKENS) ? TOKENS : (int)((maxRows / 256) * 256);
    if (chunk < 256) chunk = 256;
    float* Pp = (float*)(Aw + (size_t)chunk * KTOT);

    prep_b_kernel<<<(OUT_F * (KTOT / 8)) / 256, 256, 0, stream>>>(W, spl, Bw);

    for (int t0 = 0; t0 < TOKENS; t0 += chunk) {
        int rows = (TOKENS - t0 < chunk) ? (TOKENS - t0) : chunk;
        prep_a_kernel<<<(rows * IN_F) / 256, 256, 0, stream>>>(
            x + (size_t)t0 * IN_F, grid, Aw);
        gemm_kan2<<<(rows >> 8) * 8, 512, 0, stream>>>(Aw, Bw, Pp, rows);
        int n4 = rows * 256;
        int rblocks = (n4 + 255) / 256; if (rblocks > 2048) rblocks = 2048;
        reduce_kan<<<rblocks, 256, 0, stream>>>(
            Pp, bias, out + (size_t)t0 * OUT_F, n4, n4);
    }
}